// Round 9
// baseline (498.508 us; speedup 1.0000x reference)
//
#include <hip/hip_runtime.h>
#include <math.h>

#define N_NODES 100000
#define N_EDGES 1600000
#define NBLK 391   // ceil(100000/256)
#define PLANE_U32 800000        // dwords per 16-feat plane (100000 nodes * 8 dwords)
#define PLANE_U16 1600000       // shorts per plane

typedef __attribute__((ext_vector_type(8))) short bf16x8;   // MFMA A/B frag (8 bf16)
typedef __attribute__((ext_vector_type(4))) float f32x4;    // MFMA C/D frag

__device__ __forceinline__ unsigned short f2bf(float f) {   // RNE fp32->bf16
    unsigned int u = __float_as_uint(f);
    u += 0x7FFF + ((u >> 16) & 1);
    return (unsigned short)(u >> 16);
}
__device__ __forceinline__ float bf_lo(unsigned int u) { return __uint_as_float(u << 16); }
__device__ __forceinline__ float bf_hi(unsigned int u) { return __uint_as_float(u & 0xFFFF0000u); }

// ---------------- CSR build ----------------

__global__ __launch_bounds__(256) void zero_cnt_kernel(int* __restrict__ cnt) {
    int i = blockIdx.x * 256 + threadIdx.x;
    if (i < N_NODES) cnt[i] = 0;
}

// enc[e] = src | (rank<<17): src < 2^17, rank < 2^15 (max in-deg ~45 for Poisson(16)).
__global__ __launch_bounds__(256) void deg_count_rank_kernel(const int* __restrict__ src,
                                                             const int* __restrict__ dst,
                                                             int* __restrict__ cnt,
                                                             int* __restrict__ enc) {
    int e = blockIdx.x * 256 + threadIdx.x;
    if (e < N_EDGES) {
        int r = atomicAdd(&cnt[dst[e]], 1);
        enc[e] = src[e] | (r << 17);
    }
}

// Fused: dis[i] = rsqrt(deg+1), then per-block exclusive scan of cnt (+ block totals).
__global__ __launch_bounds__(256) void scan_blk_dis_kernel(int* __restrict__ cnt,
                                                           int* __restrict__ blk,
                                                           float* __restrict__ dis) {
    __shared__ int s[256];
    int t = threadIdx.x, i = blockIdx.x * 256 + t;
    int v = (i < N_NODES) ? cnt[i] : 0;
    if (i < N_NODES) dis[i] = rsqrtf((float)v + 1.0f);
    s[t] = v;
    __syncthreads();
    for (int off = 1; off < 256; off <<= 1) {
        int u = (t >= off) ? s[t - off] : 0;
        __syncthreads();
        s[t] += u;
        __syncthreads();
    }
    if (i < N_NODES) cnt[i] = s[t] - v;           // exclusive within block
    if (t == 255) blk[blockIdx.x] = s[255];
}

__global__ __launch_bounds__(512) void scan_top_kernel(int* __restrict__ blk) {
    __shared__ int s[512];
    int t = threadIdx.x;
    int v = (t < NBLK) ? blk[t] : 0;
    s[t] = v;
    __syncthreads();
    for (int off = 1; off < 512; off <<= 1) {
        int u = (t >= off) ? s[t - off] : 0;
        __syncthreads();
        s[t] += u;
        __syncthreads();
    }
    if (t < NBLK) blk[t] = s[t] - v;
}

// start(d) = cnt[d] + blk[d>>8]. Atomic-free placement.
__global__ __launch_bounds__(256) void place_kernel(const int* __restrict__ dst,
                                                    const int* __restrict__ enc,
                                                    const int* __restrict__ cnt,
                                                    const int* __restrict__ blk,
                                                    int* __restrict__ col) {
    int e = blockIdx.x * 256 + threadIdx.x;
    int d = dst[e];
    int v = enc[e];
    col[cnt[d] + blk[d >> 8] + (v >> 17)] = v & 0x1FFFF;
}

// ---------------- converts: x -> plane-major bf16, W1T/W2T -> bf16 ----------------
// xb plane f (16 feats) is a contiguous 3.2 MB block: xb[f*PLANE + node*16 + (feat%16)].

__global__ __launch_bounds__(256) void convert_xw_kernel(const float* __restrict__ x,
                                                         const float* __restrict__ W1,
                                                         const float* __restrict__ W2,
                                                         ushort* __restrict__ xb,
                                                         ushort* __restrict__ W1T,
                                                         ushort* __restrict__ W2T) {
    if (blockIdx.x < 12500) {
        int i = blockIdx.x * 256 + threadIdx.x;   // one float4 -> 4 bf16
        int node = i >> 5;
        int c = (i & 31) << 2;                    // feat start: 0..124
        float4 v = *(const float4*)&x[i * 4];
        ushort4 o;
        o.x = f2bf(v.x); o.y = f2bf(v.y); o.z = f2bf(v.z); o.w = f2bf(v.w);
        *(ushort4*)&xb[(c >> 4) * PLANE_U16 + node * 16 + (c & 15)] = o;
    } else {
        int j = (blockIdx.x - 12500) * 256 + threadIdx.x;   // 72 blocks * 256 = 18432
        if (j < 16384) {
            int k = j >> 7, n = j & 127;                     // W1[k][n] -> W1T[n][k]
            W1T[n * 128 + k] = f2bf(W1[j]);
        } else {
            int q = j - 16384;                               // 2048 elements
            int k = q >> 4, n = q & 15;                      // W2[k][n] -> W2T[n][k]
            W2T[n * 128 + k] = f2bf(W2[q]);
        }
    }
}

// ---------------- layer-1 aggregation (feature-sliced, wave-uniform node) ----------------
// One (node, slice) pair per WAVE: 64 lanes = 8 edges x 8 dwords. slice = blockIdx&7 pins
// the 3.2 MB xb plane to one XCD's L2. Trip count wave-uniform; col loads coalesced 32 B;
// edge rows: 8x32 B requests per instruction. 16 edges/iter (2 independent chains).

__global__ __launch_bounds__(256) void gather1_kernel(const int* __restrict__ col,
                                                      const int* __restrict__ cnt,
                                                      const int* __restrict__ blk,
                                                      const float* __restrict__ dis,
                                                      const unsigned int* __restrict__ xb,
                                                      unsigned int* __restrict__ xa) {
    int t = threadIdx.x;
    int wave = t >> 6, lane = t & 63;
    int slice = blockIdx.x & 7;                  // XCD pin (speed heuristic only)
    int node = (blockIdx.x >> 3) * 4 + wave;     // 200000 blocks / 8 slices * 4 waves
    int g = lane >> 3;                           // edge sub-group 0..7
    int j = lane & 7;                            // dword (2 feats) within 32 B row segment
    const unsigned int* xp = xb + slice * PLANE_U32;
    int beg = cnt[node] + blk[node >> 8];
    int end = (node == N_NODES - 1) ? N_EDGES : cnt[node + 1] + blk[(node + 1) >> 8];
    float a0x = 0.f, a0y = 0.f, a1x = 0.f, a1y = 0.f;
    for (int k = beg; k < end; k += 16) {        // loop entered only if end > beg
        int i0 = k + g, i1 = k + 8 + g;
        int c0 = (i0 < end) ? i0 : end - 1;      // end-1 >= beg >= 0 when entered
        int c1 = (i1 < end) ? i1 : end - 1;
        int s0 = col[c0];
        int s1 = col[c1];
        float w0 = (i0 < end) ? dis[s0] : 0.f;
        float w1 = (i1 < end) ? dis[s1] : 0.f;
        unsigned int u0 = xp[s0 * 8 + j];
        unsigned int u1 = xp[s1 * 8 + j];
        a0x += bf_lo(u0) * w0; a0y += bf_hi(u0) * w0;
        a1x += bf_lo(u1) * w1; a1y += bf_hi(u1) * w1;
    }
    float ax = a0x + a1x, ay = a0y + a1y;
    // reduce across the 8 edge-groups (lanes differing in bits 3..5); j preserved
    ax += __shfl_xor(ax, 8);  ay += __shfl_xor(ay, 8);
    ax += __shfl_xor(ax, 16); ay += __shfl_xor(ay, 16);
    ax += __shfl_xor(ax, 32); ay += __shfl_xor(ay, 32);
    if (lane < 8) {
        float dn = dis[node];
        unsigned int su = xp[node * 8 + lane];   // self-loop term
        float rx = (ax + bf_lo(su) * dn) * dn;
        float ry = (ay + bf_hi(su) * dn) * dn;
        xa[slice * PLANE_U32 + node * 8 + lane] =
            (unsigned int)f2bf(rx) | ((unsigned int)f2bf(ry) << 16);
    }
}

// ---------------- fused MLP: h2 = relu(xa@W1 + b1) @ W2, h2 emitted as bf16 ----------------
// xa is plane-major: feats [kk*32+quad*8, +8) live in plane 2*kk+(quad>>1), offset (quad&1)*16B.

__global__ __launch_bounds__(256) void mlp_kernel(const ushort* __restrict__ xa,
                                                  const ushort* __restrict__ W1T,
                                                  const float* __restrict__ b1,
                                                  const ushort* __restrict__ W2T,
                                                  ushort* __restrict__ h2b) {
    __shared__ ushort sh[4][16][136];   // 136: keeps ds_read_b128 16B-aligned, banks spread
    int t = threadIdx.x;
    int wave = t >> 6, lane = t & 63;
    int l = lane & 15, quad = lane >> 4;
    int m0 = blockIdx.x * 64 + wave * 16;        // 1563*64 = 100032; waves past end idle
    bool valid = (m0 < N_NODES);                 // whole-wave predicate (no early return!)
    int row = valid ? (m0 + l) : 0;

    f32x4 acc[8] = {};
    #pragma unroll
    for (int kk = 0; kk < 4; ++kk) {
        int plane = 2 * kk + (quad >> 1);
        bf16x8 a = *(const bf16x8*)&xa[plane * PLANE_U16 + row * 16 + (quad & 1) * 8];
        #pragma unroll
        for (int nt = 0; nt < 8; ++nt) {
            bf16x8 b = *(const bf16x8*)&W1T[(nt * 16 + l) * 128 + kk * 32 + quad * 8];
            acc[nt] = __builtin_amdgcn_mfma_f32_16x16x32_bf16(a, b, acc[nt], 0, 0, 0);
        }
    }
    #pragma unroll
    for (int nt = 0; nt < 8; ++nt) {
        float bias = b1[nt * 16 + l];
        #pragma unroll
        for (int r = 0; r < 4; ++r)
            sh[wave][quad * 4 + r][nt * 16 + l] = f2bf(fmaxf(acc[nt][r] + bias, 0.0f));
    }
    __syncthreads();   // all waves present — orders LDS writes->reads

    f32x4 acc2 = {};
    #pragma unroll
    for (int kk = 0; kk < 4; ++kk) {
        bf16x8 a2 = *(const bf16x8*)&sh[wave][l][kk * 32 + quad * 8];
        bf16x8 bw = *(const bf16x8*)&W2T[l * 128 + kk * 32 + quad * 8];
        acc2 = __builtin_amdgcn_mfma_f32_16x16x32_bf16(a2, bw, acc2, 0, 0, 0);
    }
    if (valid) {
        #pragma unroll
        for (int r = 0; r < 4; ++r)
            h2b[(m0 + quad * 4 + r) * 16 + l] = f2bf(acc2[r]);   // h2[m][n=l]
    }
}

// ---------------- layer-2 gather + bias + log-softmax (bf16 h2 table, 8 lanes/node) ----------------

__global__ __launch_bounds__(256) void gather2_lsm_kernel(const int* __restrict__ col,
                                                          const int* __restrict__ cnt,
                                                          const int* __restrict__ blk,
                                                          const float* __restrict__ dis,
                                                          const unsigned int* __restrict__ h2p,
                                                          const float* __restrict__ b2,
                                                          float* __restrict__ out) {
    int t = threadIdx.x;
    int node = blockIdx.x * 32 + (t >> 3);       // 3125 * 32 = 100000 exact
    int c = t & 7;                               // class pair: (2c, 2c+1)
    float dn = dis[node];
    int beg = cnt[node] + blk[node >> 8];
    int end = (node == N_NODES - 1) ? N_EDGES : cnt[node + 1] + blk[(node + 1) >> 8];
    unsigned int su = h2p[node * 8 + c];
    float a0x = bf_lo(su) * dn, a0y = bf_hi(su) * dn;    // self-loop term
    float a1x = 0.f, a1y = 0.f, a2x = 0.f, a2y = 0.f, a3x = 0.f, a3y = 0.f;
    int k = beg;
    for (; k + 4 <= end; k += 4) {
        int s0 = col[k], s1 = col[k + 1], s2 = col[k + 2], s3 = col[k + 3];
        float w0 = dis[s0], w1 = dis[s1], w2 = dis[s2], w3 = dis[s3];
        unsigned int u0 = h2p[s0 * 8 + c], u1 = h2p[s1 * 8 + c];
        unsigned int u2 = h2p[s2 * 8 + c], u3 = h2p[s3 * 8 + c];
        a0x += bf_lo(u0) * w0; a0y += bf_hi(u0) * w0;
        a1x += bf_lo(u1) * w1; a1y += bf_hi(u1) * w1;
        a2x += bf_lo(u2) * w2; a2y += bf_hi(u2) * w2;
        a3x += bf_lo(u3) * w3; a3y += bf_hi(u3) * w3;
    }
    for (; k < end; ++k) {
        int s = col[k];
        float w = dis[s];
        unsigned int u = h2p[s * 8 + c];
        a0x += bf_lo(u) * w; a0y += bf_hi(u) * w;
    }
    float2 bb = ((const float2*)b2)[c];
    float v0 = ((a0x + a1x) + (a2x + a3x)) * dn + bb.x;
    float v1 = ((a0y + a1y) + (a2y + a3y)) * dn + bb.y;
    float m = fmaxf(v0, v1);
    #pragma unroll
    for (int off = 1; off < 8; off <<= 1) m = fmaxf(m, __shfl_xor(m, off, 8));
    float ssum = expf(v0 - m) + expf(v1 - m);
    #pragma unroll
    for (int off = 1; off < 8; off <<= 1) ssum += __shfl_xor(ssum, off, 8);
    float lg = m + logf(ssum);
    ((float2*)out)[node * 8 + c] = make_float2(v0 - lg, v1 - lg);
}

// ---------------- launch ----------------

extern "C" void kernel_launch(void* const* d_in, const int* in_sizes, int n_in,
                              void* d_out, int out_size, void* d_ws, size_t ws_size,
                              hipStream_t stream) {
    const float* x  = (const float*)d_in[0];
    const int*   ei = (const int*)d_in[1];
    const float* W1 = (const float*)d_in[2];
    const float* b1 = (const float*)d_in[3];
    const float* W2 = (const float*)d_in[4];
    const float* b2 = (const float*)d_in[5];
    float* out = (float*)d_out;

    const int* src = ei;              // edge_index[0]
    const int* dst = ei + N_EDGES;    // edge_index[1]

    // workspace (bytes), TOTAL = 58,440,960 (unchanged, proven safe R2-R8).
    // offset 0 timeline: enc (CSR) -> xb planes (convert->gather1) -> h2b (mlp->gather2)
    char* ws = (char*)d_ws;
    int*    enc = (int*)   (ws + 0);            //  6,400,000
    ushort* xb  = (ushort*)(ws + 0);            // 25,600,000 (8 planes x 3.2 MB)
    ushort* h2b = (ushort*)(ws + 0);            //  3,200,000
    ushort* xa  = (ushort*)(ws + 25600000);     // 25,600,000 (8 planes x 3.2 MB)
    int*    col = (int*)   (ws + 51200000);     //  6,400,000
    float*  dis = (float*) (ws + 57600000);     //    400,000
    int*    cnt = (int*)   (ws + 58000000);     //    400,000
    int*    blk = (int*)   (ws + 58400000);     //      1,564
    ushort* W1T = (ushort*)(ws + 58404096);     //     32,768
    ushort* W2T = (ushort*)(ws + 58436864);     //      4,096

    zero_cnt_kernel      <<<NBLK, 256, 0, stream>>>(cnt);
    deg_count_rank_kernel<<<N_EDGES / 256, 256, 0, stream>>>(src, dst, cnt, enc);
    scan_blk_dis_kernel  <<<NBLK, 256, 0, stream>>>(cnt, blk, dis);
    scan_top_kernel      <<<1, 512, 0, stream>>>(blk);
    place_kernel         <<<N_EDGES / 256, 256, 0, stream>>>(dst, enc, cnt, blk, col);

    convert_xw_kernel    <<<12572, 256, 0, stream>>>(x, W1, W2, xb, W1T, W2T);  // after place (enc dead)

    gather1_kernel       <<<200000, 256, 0, stream>>>(col, cnt, blk, dis,
                                                      (const unsigned int*)xb,
                                                      (unsigned int*)xa);
    mlp_kernel           <<<1563, 256, 0, stream>>>(xa, W1T, b1, W2T, h2b);     // h2b overwrites dead xb
    gather2_lsm_kernel   <<<3125, 256, 0, stream>>>(col, cnt, blk, dis,
                                                    (const unsigned int*)h2b, b2, out);
}

// Round 10
// 329.208 us; speedup vs baseline: 1.5143x; 1.5143x over previous
//
#include <hip/hip_runtime.h>
#include <math.h>

#define N_NODES 100000
#define N_EDGES 1600000
#define NBLK 391   // ceil(100000/256)
#define DSLICE 12500   // nodes per dst-slice (8 slices)

typedef __attribute__((ext_vector_type(8))) short bf16x8;   // MFMA A/B frag (8 bf16)
typedef __attribute__((ext_vector_type(4))) float f32x4;    // MFMA C/D frag

__device__ __forceinline__ unsigned short f2bf(float f) {   // RNE fp32->bf16
    unsigned int u = __float_as_uint(f);
    u += 0x7FFF + ((u >> 16) & 1);
    return (unsigned short)(u >> 16);
}
__device__ __forceinline__ float bf_lo(unsigned int u) { return __uint_as_float(u << 16); }
__device__ __forceinline__ float bf_hi(unsigned int u) { return __uint_as_float(u & 0xFFFF0000u); }

// ---------------- CSR build ----------------

__global__ __launch_bounds__(256) void zero_cnt_kernel(int* __restrict__ cnt) {
    int i = blockIdx.x * 256 + threadIdx.x;
    if (i < N_NODES) cnt[i] = 0;
}

// enc[e] = src | (rank<<17): src < 2^17, rank < 2^15 (max in-deg ~45 for Poisson(16)).
// Returning atomic, but dependent store (enc) is coalesced -> TLP-hidden.
__global__ __launch_bounds__(256) void deg_count_rank_kernel(const int* __restrict__ src,
                                                             const int* __restrict__ dst,
                                                             int* __restrict__ cnt,
                                                             int* __restrict__ enc) {
    int e = blockIdx.x * 256 + threadIdx.x;
    if (e < N_EDGES) {
        int r = atomicAdd(&cnt[dst[e]], 1);
        enc[e] = src[e] | (r << 17);
    }
}

// Fused: dis[i] = rsqrt(deg+1), then per-block exclusive scan of cnt (+ block totals).
__global__ __launch_bounds__(256) void scan_blk_dis_kernel(int* __restrict__ cnt,
                                                           int* __restrict__ blk,
                                                           float* __restrict__ dis) {
    __shared__ int s[256];
    int t = threadIdx.x, i = blockIdx.x * 256 + t;
    int v = (i < N_NODES) ? cnt[i] : 0;
    if (i < N_NODES) dis[i] = rsqrtf((float)v + 1.0f);
    s[t] = v;
    __syncthreads();
    for (int off = 1; off < 256; off <<= 1) {
        int u = (t >= off) ? s[t - off] : 0;
        __syncthreads();
        s[t] += u;
        __syncthreads();
    }
    if (i < N_NODES) cnt[i] = s[t] - v;           // exclusive within block
    if (t == 255) blk[blockIdx.x] = s[255];
}

__global__ __launch_bounds__(512) void scan_top_kernel(int* __restrict__ blk) {
    __shared__ int s[512];
    int t = threadIdx.x;
    int v = (t < NBLK) ? blk[t] : 0;
    s[t] = v;
    __syncthreads();
    for (int off = 1; off < 512; off <<= 1) {
        int u = (t >= off) ? s[t - off] : 0;
        __syncthreads();
        s[t] += u;
        __syncthreads();
    }
    if (t < NBLK) blk[t] = s[t] - v;
}

// XCD-pinned, dst-sliced, atomic-free placement. slice = blockIdx&7 (XCD round-robin):
// slice s only places edges with dst in [s*12500, +12500), so each dst's contiguous col
// segment (one 64 B line) is written by ONE XCD -> no cross-XCD line ping-pong.
// (R4 evidence: unsliced version had WRITE_SIZE 105 MB = every 4 B store a line writeback.)
__global__ __launch_bounds__(256) void place8_kernel(const int* __restrict__ dst,
                                                     const int* __restrict__ enc,
                                                     const int* __restrict__ cnt,
                                                     const int* __restrict__ blk,
                                                     int* __restrict__ col) {
    int slice = blockIdx.x & 7;
    int e = (blockIdx.x >> 3) * 256 + threadIdx.x;   // 6250 chunks * 256 = 1.6M exact
    int d = dst[e];
    int lo = slice * DSLICE;
    if ((unsigned)(d - lo) < DSLICE) {
        int v = enc[e];
        col[cnt[d] + blk[d >> 8] + (v >> 17)] = v & 0x1FFFF;
    }
}

// ---------------- converts: x -> node-major bf16, W1T/W2T -> bf16 ----------------

__global__ __launch_bounds__(256) void convert_xw_kernel(const float* __restrict__ x,
                                                         const float* __restrict__ W1,
                                                         const float* __restrict__ W2,
                                                         ushort* __restrict__ xb,
                                                         ushort* __restrict__ W1T,
                                                         ushort* __restrict__ W2T) {
    if (blockIdx.x < 12500) {
        int i = blockIdx.x * 256 + threadIdx.x;
        float4 v = *(const float4*)&x[i * 4];
        ushort4 o;
        o.x = f2bf(v.x); o.y = f2bf(v.y); o.z = f2bf(v.z); o.w = f2bf(v.w);
        *(ushort4*)&xb[i * 4] = o;
    } else {
        int j = (blockIdx.x - 12500) * 256 + threadIdx.x;   // 72 blocks * 256 = 18432
        if (j < 16384) {
            int k = j >> 7, n = j & 127;                     // W1[k][n] -> W1T[n][k]
            W1T[n * 128 + k] = f2bf(W1[j]);
        } else {
            int q = j - 16384;                               // 2048 elements
            int k = q >> 4, n = q & 15;                      // W2[k][n] -> W2T[n][k]
            W2T[n * 128 + k] = f2bf(W2[q]);
        }
    }
}

// ---------------- layer-1 aggregation (R6 form: wave=node, 64 lanes=128 feats) ----------------
// Proven 74 us @ FETCH 194 MB. 8-deep unroll, coalesced 256 B row reads.

__global__ __launch_bounds__(256) void gather1_kernel(const int* __restrict__ col,
                                                      const int* __restrict__ cnt,
                                                      const int* __restrict__ blk,
                                                      const float* __restrict__ dis,
                                                      const unsigned int* __restrict__ xb,
                                                      unsigned int* __restrict__ xa) {
    int t = threadIdx.x;
    int node = blockIdx.x * 4 + (t >> 6);        // 25000 blocks * 4 = 100000 exact
    int lane = t & 63;
    float dn = dis[node];
    int beg = cnt[node] + blk[node >> 8];
    int end = (node == N_NODES - 1) ? N_EDGES : cnt[node + 1] + blk[(node + 1) >> 8];
    unsigned int su = xb[node * 64 + lane];
    float a0x = bf_lo(su) * dn, a0y = bf_hi(su) * dn;
    float a1x = 0.f, a1y = 0.f, a2x = 0.f, a2y = 0.f, a3x = 0.f, a3y = 0.f;
    float a4x = 0.f, a4y = 0.f, a5x = 0.f, a5y = 0.f, a6x = 0.f, a6y = 0.f, a7x = 0.f, a7y = 0.f;
    int k = beg;
    for (; k + 8 <= end; k += 8) {
        int s0 = col[k], s1 = col[k + 1], s2 = col[k + 2], s3 = col[k + 3];
        int s4 = col[k + 4], s5 = col[k + 5], s6 = col[k + 6], s7 = col[k + 7];
        float w0 = dis[s0], w1 = dis[s1], w2 = dis[s2], w3 = dis[s3];
        float w4 = dis[s4], w5 = dis[s5], w6 = dis[s6], w7 = dis[s7];
        unsigned int u0 = xb[s0 * 64 + lane], u1 = xb[s1 * 64 + lane];
        unsigned int u2 = xb[s2 * 64 + lane], u3 = xb[s3 * 64 + lane];
        unsigned int u4 = xb[s4 * 64 + lane], u5 = xb[s5 * 64 + lane];
        unsigned int u6 = xb[s6 * 64 + lane], u7 = xb[s7 * 64 + lane];
        a0x += bf_lo(u0) * w0; a0y += bf_hi(u0) * w0;
        a1x += bf_lo(u1) * w1; a1y += bf_hi(u1) * w1;
        a2x += bf_lo(u2) * w2; a2y += bf_hi(u2) * w2;
        a3x += bf_lo(u3) * w3; a3y += bf_hi(u3) * w3;
        a4x += bf_lo(u4) * w4; a4y += bf_hi(u4) * w4;
        a5x += bf_lo(u5) * w5; a5y += bf_hi(u5) * w5;
        a6x += bf_lo(u6) * w6; a6y += bf_hi(u6) * w6;
        a7x += bf_lo(u7) * w7; a7y += bf_hi(u7) * w7;
    }
    for (; k + 4 <= end; k += 4) {
        int s0 = col[k], s1 = col[k + 1], s2 = col[k + 2], s3 = col[k + 3];
        float w0 = dis[s0], w1 = dis[s1], w2 = dis[s2], w3 = dis[s3];
        unsigned int u0 = xb[s0 * 64 + lane], u1 = xb[s1 * 64 + lane];
        unsigned int u2 = xb[s2 * 64 + lane], u3 = xb[s3 * 64 + lane];
        a0x += bf_lo(u0) * w0; a0y += bf_hi(u0) * w0;
        a1x += bf_lo(u1) * w1; a1y += bf_hi(u1) * w1;
        a2x += bf_lo(u2) * w2; a2y += bf_hi(u2) * w2;
        a3x += bf_lo(u3) * w3; a3y += bf_hi(u3) * w3;
    }
    for (; k < end; ++k) {
        int s = col[k];
        float w = dis[s];
        unsigned int u = xb[s * 64 + lane];
        a0x += bf_lo(u) * w; a0y += bf_hi(u) * w;
    }
    float rx = (((a0x + a1x) + (a2x + a3x)) + ((a4x + a5x) + (a6x + a7x))) * dn;
    float ry = (((a0y + a1y) + (a2y + a3y)) + ((a4y + a5y) + (a6y + a7y))) * dn;
    xa[node * 64 + lane] = (unsigned int)f2bf(rx) | ((unsigned int)f2bf(ry) << 16);
}

// ---------------- fused MLP: h2 = relu(xa@W1 + b1) @ W2, h2 emitted as bf16 ----------------

__global__ __launch_bounds__(256) void mlp_kernel(const ushort* __restrict__ xa,
                                                  const ushort* __restrict__ W1T,
                                                  const float* __restrict__ b1,
                                                  const ushort* __restrict__ W2T,
                                                  ushort* __restrict__ h2b) {
    __shared__ ushort sh[4][16][136];   // 136: keeps ds_read_b128 16B-aligned, banks spread
    int t = threadIdx.x;
    int wave = t >> 6, lane = t & 63;
    int l = lane & 15, quad = lane >> 4;
    int m0 = blockIdx.x * 64 + wave * 16;        // 1563*64 = 100032; waves past end idle
    bool valid = (m0 < N_NODES);                 // whole-wave predicate (no early return!)
    int row = valid ? (m0 + l) : 0;

    f32x4 acc[8] = {};
    #pragma unroll
    for (int kk = 0; kk < 4; ++kk) {
        bf16x8 a = *(const bf16x8*)&xa[row * 128 + kk * 32 + quad * 8];
        #pragma unroll
        for (int nt = 0; nt < 8; ++nt) {
            bf16x8 b = *(const bf16x8*)&W1T[(nt * 16 + l) * 128 + kk * 32 + quad * 8];
            acc[nt] = __builtin_amdgcn_mfma_f32_16x16x32_bf16(a, b, acc[nt], 0, 0, 0);
        }
    }
    #pragma unroll
    for (int nt = 0; nt < 8; ++nt) {
        float bias = b1[nt * 16 + l];
        #pragma unroll
        for (int r = 0; r < 4; ++r)
            sh[wave][quad * 4 + r][nt * 16 + l] = f2bf(fmaxf(acc[nt][r] + bias, 0.0f));
    }
    __syncthreads();   // all waves present — orders LDS writes->reads

    f32x4 acc2 = {};
    #pragma unroll
    for (int kk = 0; kk < 4; ++kk) {
        bf16x8 a2 = *(const bf16x8*)&sh[wave][l][kk * 32 + quad * 8];
        bf16x8 bw = *(const bf16x8*)&W2T[l * 128 + kk * 32 + quad * 8];
        acc2 = __builtin_amdgcn_mfma_f32_16x16x32_bf16(a2, bw, acc2, 0, 0, 0);
    }
    if (valid) {
        #pragma unroll
        for (int r = 0; r < 4; ++r)
            h2b[(m0 + quad * 4 + r) * 16 + l] = f2bf(acc2[r]);   // h2[m][n=l]
    }
}

// ---------------- layer-2 gather + bias + log-softmax (bf16 h2 table, 8 lanes/node) ----------------

__global__ __launch_bounds__(256) void gather2_lsm_kernel(const int* __restrict__ col,
                                                          const int* __restrict__ cnt,
                                                          const int* __restrict__ blk,
                                                          const float* __restrict__ dis,
                                                          const unsigned int* __restrict__ h2p,
                                                          const float* __restrict__ b2,
                                                          float* __restrict__ out) {
    int t = threadIdx.x;
    int node = blockIdx.x * 32 + (t >> 3);       // 3125 * 32 = 100000 exact
    int c = t & 7;                               // class pair: (2c, 2c+1)
    float dn = dis[node];
    int beg = cnt[node] + blk[node >> 8];
    int end = (node == N_NODES - 1) ? N_EDGES : cnt[node + 1] + blk[(node + 1) >> 8];
    unsigned int su = h2p[node * 8 + c];
    float a0x = bf_lo(su) * dn, a0y = bf_hi(su) * dn;    // self-loop term
    float a1x = 0.f, a1y = 0.f, a2x = 0.f, a2y = 0.f, a3x = 0.f, a3y = 0.f;
    int k = beg;
    for (; k + 4 <= end; k += 4) {
        int s0 = col[k], s1 = col[k + 1], s2 = col[k + 2], s3 = col[k + 3];
        float w0 = dis[s0], w1 = dis[s1], w2 = dis[s2], w3 = dis[s3];
        unsigned int u0 = h2p[s0 * 8 + c], u1 = h2p[s1 * 8 + c];
        unsigned int u2 = h2p[s2 * 8 + c], u3 = h2p[s3 * 8 + c];
        a0x += bf_lo(u0) * w0; a0y += bf_hi(u0) * w0;
        a1x += bf_lo(u1) * w1; a1y += bf_hi(u1) * w1;
        a2x += bf_lo(u2) * w2; a2y += bf_hi(u2) * w2;
        a3x += bf_lo(u3) * w3; a3y += bf_hi(u3) * w3;
    }
    for (; k < end; ++k) {
        int s = col[k];
        float w = dis[s];
        unsigned int u = h2p[s * 8 + c];
        a0x += bf_lo(u) * w; a0y += bf_hi(u) * w;
    }
    float2 bb = ((const float2*)b2)[c];
    float v0 = ((a0x + a1x) + (a2x + a3x)) * dn + bb.x;
    float v1 = ((a0y + a1y) + (a2y + a3y)) * dn + bb.y;
    float m = fmaxf(v0, v1);
    #pragma unroll
    for (int off = 1; off < 8; off <<= 1) m = fmaxf(m, __shfl_xor(m, off, 8));
    float ssum = expf(v0 - m) + expf(v1 - m);
    #pragma unroll
    for (int off = 1; off < 8; off <<= 1) ssum += __shfl_xor(ssum, off, 8);
    float lg = m + logf(ssum);
    ((float2*)out)[node * 8 + c] = make_float2(v0 - lg, v1 - lg);
}

// ---------------- launch ----------------

extern "C" void kernel_launch(void* const* d_in, const int* in_sizes, int n_in,
                              void* d_out, int out_size, void* d_ws, size_t ws_size,
                              hipStream_t stream) {
    const float* x  = (const float*)d_in[0];
    const int*   ei = (const int*)d_in[1];
    const float* W1 = (const float*)d_in[2];
    const float* b1 = (const float*)d_in[3];
    const float* W2 = (const float*)d_in[4];
    const float* b2 = (const float*)d_in[5];
    float* out = (float*)d_out;

    const int* src = ei;              // edge_index[0]
    const int* dst = ei + N_EDGES;    // edge_index[1]

    // workspace (bytes), TOTAL = 58,440,960 (unchanged, proven safe R2-R8).
    // offset 0 timeline: enc (CSR) -> xb bf16 (convert->gather1) -> h2b (mlp->gather2)
    char* ws = (char*)d_ws;
    int*    enc = (int*)   (ws + 0);            //  6,400,000
    ushort* xb  = (ushort*)(ws + 0);            // 25,600,000 (node-major)
    ushort* h2b = (ushort*)(ws + 0);            //  3,200,000
    ushort* xa  = (ushort*)(ws + 25600000);     // 25,600,000 (node-major)
    int*    col = (int*)   (ws + 51200000);     //  6,400,000
    float*  dis = (float*) (ws + 57600000);     //    400,000
    int*    cnt = (int*)   (ws + 58000000);     //    400,000
    int*    blk = (int*)   (ws + 58400000);     //      1,564
    ushort* W1T = (ushort*)(ws + 58404096);     //     32,768
    ushort* W2T = (ushort*)(ws + 58436864);     //      4,096

    zero_cnt_kernel      <<<NBLK, 256, 0, stream>>>(cnt);
    deg_count_rank_kernel<<<N_EDGES / 256, 256, 0, stream>>>(src, dst, cnt, enc);
    scan_blk_dis_kernel  <<<NBLK, 256, 0, stream>>>(cnt, blk, dis);
    scan_top_kernel      <<<1, 512, 0, stream>>>(blk);
    place8_kernel        <<<8 * (N_EDGES / 256), 256, 0, stream>>>(dst, enc, cnt, blk, col);

    convert_xw_kernel    <<<12572, 256, 0, stream>>>(x, W1, W2, xb, W1T, W2T);  // after place (enc dead)

    gather1_kernel       <<<N_NODES / 4, 256, 0, stream>>>(col, cnt, blk, dis,
                                                           (const unsigned int*)xb,
                                                           (unsigned int*)xa);
    mlp_kernel           <<<1563, 256, 0, stream>>>(xa, W1T, b1, W2T, h2b);     // h2b overwrites dead xb
    gather2_lsm_kernel   <<<3125, 256, 0, stream>>>(col, cnt, blk, dis,
                                                    (const unsigned int*)h2b, b2, out);
}

// Round 11
// 321.076 us; speedup vs baseline: 1.5526x; 1.0253x over previous
//
#include <hip/hip_runtime.h>
#include <math.h>

#define N_NODES 100000
#define N_EDGES 1600000
#define NBLK 391   // ceil(100000/256)

typedef __attribute__((ext_vector_type(8))) short bf16x8;   // MFMA A/B frag (8 bf16)
typedef __attribute__((ext_vector_type(4))) float f32x4;    // MFMA C/D frag
typedef __attribute__((ext_vector_type(2))) float f32x2;    // packed pair -> v_pk_fma_f32

__device__ __forceinline__ unsigned short f2bf(float f) {   // RNE fp32->bf16
    unsigned int u = __float_as_uint(f);
    u += 0x7FFF + ((u >> 16) & 1);
    return (unsigned short)(u >> 16);
}
__device__ __forceinline__ float bf_lo(unsigned int u) { return __uint_as_float(u << 16); }
__device__ __forceinline__ float bf_hi(unsigned int u) { return __uint_as_float(u & 0xFFFF0000u); }
__device__ __forceinline__ f32x2 bfpair(unsigned int u) {
    f32x2 r; r.x = bf_lo(u); r.y = bf_hi(u); return r;
}

// ---------------- CSR build ----------------

__global__ __launch_bounds__(256) void zero_cnt_kernel(int* __restrict__ cnt) {
    int i = blockIdx.x * 256 + threadIdx.x;
    if (i < N_NODES) cnt[i] = 0;
}

// Merged: deg_count_rank (blocks 0..6249, atomics start early) + x->bf16 convert
// (blocks 6250..18749, streaming keeps CUs busy behind atomic latency) + W converts.
// enc[e] = src | (rank<<17): src < 2^17, rank < 2^15 (max in-deg ~45 for Poisson(16)).
__global__ __launch_bounds__(256) void convert_deg_kernel(const float* __restrict__ x,
                                                          const float* __restrict__ W1,
                                                          const float* __restrict__ W2,
                                                          const int* __restrict__ src,
                                                          const int* __restrict__ dst,
                                                          ushort* __restrict__ xb,
                                                          ushort* __restrict__ W1T,
                                                          ushort* __restrict__ W2T,
                                                          int* __restrict__ cnt,
                                                          int* __restrict__ enc) {
    int b = blockIdx.x;
    if (b < 6250) {                                   // deg + rank capture
        int e = b * 256 + threadIdx.x;
        int r = atomicAdd(&cnt[dst[e]], 1);
        enc[e] = src[e] | (r << 17);
    } else if (b < 18750) {                           // x -> bf16 (node-major)
        int i = (b - 6250) * 256 + threadIdx.x;       // 12500 blocks, one float4 each
        float4 v = *(const float4*)&x[i * 4];
        ushort4 o;
        o.x = f2bf(v.x); o.y = f2bf(v.y); o.z = f2bf(v.z); o.w = f2bf(v.w);
        *(ushort4*)&xb[i * 4] = o;
    } else {                                          // 72 blocks: W1T / W2T
        int j = (b - 18750) * 256 + threadIdx.x;
        if (j < 16384) {
            int k = j >> 7, n = j & 127;              // W1[k][n] -> W1T[n][k]
            W1T[n * 128 + k] = f2bf(W1[j]);
        } else {
            int q = j - 16384;                        // 2048 elements
            int k = q >> 4, n = q & 15;               // W2[k][n] -> W2T[n][k]
            W2T[n * 128 + k] = f2bf(W2[q]);
        }
    }
}

// Fused: dis[i] = rsqrt(deg+1), then per-block exclusive scan of cnt (+ block totals).
__global__ __launch_bounds__(256) void scan_blk_dis_kernel(int* __restrict__ cnt,
                                                           int* __restrict__ blk,
                                                           float* __restrict__ dis) {
    __shared__ int s[256];
    int t = threadIdx.x, i = blockIdx.x * 256 + t;
    int v = (i < N_NODES) ? cnt[i] : 0;
    if (i < N_NODES) dis[i] = rsqrtf((float)v + 1.0f);
    s[t] = v;
    __syncthreads();
    for (int off = 1; off < 256; off <<= 1) {
        int u = (t >= off) ? s[t - off] : 0;
        __syncthreads();
        s[t] += u;
        __syncthreads();
    }
    if (i < N_NODES) cnt[i] = s[t] - v;           // exclusive within block
    if (t == 255) blk[blockIdx.x] = s[255];
}

__global__ __launch_bounds__(512) void scan_top_kernel(int* __restrict__ blk) {
    __shared__ int s[512];
    int t = threadIdx.x;
    int v = (t < NBLK) ? blk[t] : 0;
    s[t] = v;
    __syncthreads();
    for (int off = 1; off < 512; off <<= 1) {
        int u = (t >= off) ? s[t - off] : 0;
        __syncthreads();
        s[t] += u;
        __syncthreads();
    }
    if (t < NBLK) blk[t] = s[t] - v;
}

// Atomic-free placement (R5-R7 proven; place8 dst-slicing was neutral -> reverted).
__global__ __launch_bounds__(256) void place_kernel(const int* __restrict__ dst,
                                                    const int* __restrict__ enc,
                                                    const int* __restrict__ cnt,
                                                    const int* __restrict__ blk,
                                                    int* __restrict__ col) {
    int e = blockIdx.x * 256 + threadIdx.x;
    int d = dst[e];
    int v = enc[e];
    col[cnt[d] + blk[d >> 8] + (v >> 17)] = v & 0x1FFFF;
}

// ---------------- layer-1 aggregation (wave=node, 64 lanes=128 feats, pk-fma) ----------------

__global__ __launch_bounds__(256) void gather1_kernel(const int* __restrict__ col,
                                                      const int* __restrict__ cnt,
                                                      const int* __restrict__ blk,
                                                      const float* __restrict__ dis,
                                                      const unsigned int* __restrict__ xb,
                                                      unsigned int* __restrict__ xa) {
    int t = threadIdx.x;
    int node = blockIdx.x * 4 + (t >> 6);        // 25000 blocks * 4 = 100000 exact
    int lane = t & 63;
    float dn = dis[node];
    int beg = cnt[node] + blk[node >> 8];
    int end = (node == N_NODES - 1) ? N_EDGES : cnt[node + 1] + blk[(node + 1) >> 8];
    unsigned int su = xb[node * 64 + lane];
    f32x2 a0 = bfpair(su) * dn;
    f32x2 a1 = {0.f, 0.f}, a2 = {0.f, 0.f}, a3 = {0.f, 0.f};
    f32x2 a4 = {0.f, 0.f}, a5 = {0.f, 0.f}, a6 = {0.f, 0.f}, a7 = {0.f, 0.f};
    int k = beg;
    for (; k + 8 <= end; k += 8) {
        int s0 = col[k], s1 = col[k + 1], s2 = col[k + 2], s3 = col[k + 3];
        int s4 = col[k + 4], s5 = col[k + 5], s6 = col[k + 6], s7 = col[k + 7];
        float w0 = dis[s0], w1 = dis[s1], w2 = dis[s2], w3 = dis[s3];
        float w4 = dis[s4], w5 = dis[s5], w6 = dis[s6], w7 = dis[s7];
        unsigned int u0 = xb[s0 * 64 + lane], u1 = xb[s1 * 64 + lane];
        unsigned int u2 = xb[s2 * 64 + lane], u3 = xb[s3 * 64 + lane];
        unsigned int u4 = xb[s4 * 64 + lane], u5 = xb[s5 * 64 + lane];
        unsigned int u6 = xb[s6 * 64 + lane], u7 = xb[s7 * 64 + lane];
        a0 += bfpair(u0) * w0;
        a1 += bfpair(u1) * w1;
        a2 += bfpair(u2) * w2;
        a3 += bfpair(u3) * w3;
        a4 += bfpair(u4) * w4;
        a5 += bfpair(u5) * w5;
        a6 += bfpair(u6) * w6;
        a7 += bfpair(u7) * w7;
    }
    for (; k + 4 <= end; k += 4) {
        int s0 = col[k], s1 = col[k + 1], s2 = col[k + 2], s3 = col[k + 3];
        float w0 = dis[s0], w1 = dis[s1], w2 = dis[s2], w3 = dis[s3];
        unsigned int u0 = xb[s0 * 64 + lane], u1 = xb[s1 * 64 + lane];
        unsigned int u2 = xb[s2 * 64 + lane], u3 = xb[s3 * 64 + lane];
        a0 += bfpair(u0) * w0;
        a1 += bfpair(u1) * w1;
        a2 += bfpair(u2) * w2;
        a3 += bfpair(u3) * w3;
    }
    for (; k < end; ++k) {
        int s = col[k];
        float w = dis[s];
        a0 += bfpair(xb[s * 64 + lane]) * w;
    }
    f32x2 r = (((a0 + a1) + (a2 + a3)) + ((a4 + a5) + (a6 + a7))) * dn;
    xa[node * 64 + lane] = (unsigned int)f2bf(r.x) | ((unsigned int)f2bf(r.y) << 16);
}

// ---------------- fused MLP: h2 = relu(xa@W1 + b1) @ W2, h2 emitted as bf16 ----------------

__global__ __launch_bounds__(256) void mlp_kernel(const ushort* __restrict__ xa,
                                                  const ushort* __restrict__ W1T,
                                                  const float* __restrict__ b1,
                                                  const ushort* __restrict__ W2T,
                                                  ushort* __restrict__ h2b) {
    __shared__ ushort sh[4][16][136];   // 136: keeps ds_read_b128 16B-aligned, banks spread
    int t = threadIdx.x;
    int wave = t >> 6, lane = t & 63;
    int l = lane & 15, quad = lane >> 4;
    int m0 = blockIdx.x * 64 + wave * 16;        // 1563*64 = 100032; waves past end idle
    bool valid = (m0 < N_NODES);                 // whole-wave predicate (no early return!)
    int row = valid ? (m0 + l) : 0;

    f32x4 acc[8] = {};
    #pragma unroll
    for (int kk = 0; kk < 4; ++kk) {
        bf16x8 a = *(const bf16x8*)&xa[row * 128 + kk * 32 + quad * 8];
        #pragma unroll
        for (int nt = 0; nt < 8; ++nt) {
            bf16x8 b = *(const bf16x8*)&W1T[(nt * 16 + l) * 128 + kk * 32 + quad * 8];
            acc[nt] = __builtin_amdgcn_mfma_f32_16x16x32_bf16(a, b, acc[nt], 0, 0, 0);
        }
    }
    #pragma unroll
    for (int nt = 0; nt < 8; ++nt) {
        float bias = b1[nt * 16 + l];
        #pragma unroll
        for (int r = 0; r < 4; ++r)
            sh[wave][quad * 4 + r][nt * 16 + l] = f2bf(fmaxf(acc[nt][r] + bias, 0.0f));
    }
    __syncthreads();   // all waves present — orders LDS writes->reads

    f32x4 acc2 = {};
    #pragma unroll
    for (int kk = 0; kk < 4; ++kk) {
        bf16x8 a2 = *(const bf16x8*)&sh[wave][l][kk * 32 + quad * 8];
        bf16x8 bw = *(const bf16x8*)&W2T[l * 128 + kk * 32 + quad * 8];
        acc2 = __builtin_amdgcn_mfma_f32_16x16x32_bf16(a2, bw, acc2, 0, 0, 0);
    }
    if (valid) {
        #pragma unroll
        for (int r = 0; r < 4; ++r)
            h2b[(m0 + quad * 4 + r) * 16 + l] = f2bf(acc2[r]);   // h2[m][n=l]
    }
}

// ---------------- layer-2 gather + bias + log-softmax (bf16 h2, 8 lanes/node, pk-fma) ----------------

__global__ __launch_bounds__(256) void gather2_lsm_kernel(const int* __restrict__ col,
                                                          const int* __restrict__ cnt,
                                                          const int* __restrict__ blk,
                                                          const float* __restrict__ dis,
                                                          const unsigned int* __restrict__ h2p,
                                                          const float* __restrict__ b2,
                                                          float* __restrict__ out) {
    int t = threadIdx.x;
    int node = blockIdx.x * 32 + (t >> 3);       // 3125 * 32 = 100000 exact
    int c = t & 7;                               // class pair: (2c, 2c+1)
    float dn = dis[node];
    int beg = cnt[node] + blk[node >> 8];
    int end = (node == N_NODES - 1) ? N_EDGES : cnt[node + 1] + blk[(node + 1) >> 8];
    unsigned int su = h2p[node * 8 + c];
    f32x2 a0 = bfpair(su) * dn;                  // self-loop term
    f32x2 a1 = {0.f, 0.f}, a2 = {0.f, 0.f}, a3 = {0.f, 0.f};
    f32x2 a4 = {0.f, 0.f}, a5 = {0.f, 0.f}, a6 = {0.f, 0.f}, a7 = {0.f, 0.f};
    int k = beg;
    for (; k + 8 <= end; k += 8) {
        int s0 = col[k], s1 = col[k + 1], s2 = col[k + 2], s3 = col[k + 3];
        int s4 = col[k + 4], s5 = col[k + 5], s6 = col[k + 6], s7 = col[k + 7];
        float w0 = dis[s0], w1 = dis[s1], w2 = dis[s2], w3 = dis[s3];
        float w4 = dis[s4], w5 = dis[s5], w6 = dis[s6], w7 = dis[s7];
        unsigned int u0 = h2p[s0 * 8 + c], u1 = h2p[s1 * 8 + c];
        unsigned int u2 = h2p[s2 * 8 + c], u3 = h2p[s3 * 8 + c];
        unsigned int u4 = h2p[s4 * 8 + c], u5 = h2p[s5 * 8 + c];
        unsigned int u6 = h2p[s6 * 8 + c], u7 = h2p[s7 * 8 + c];
        a0 += bfpair(u0) * w0;
        a1 += bfpair(u1) * w1;
        a2 += bfpair(u2) * w2;
        a3 += bfpair(u3) * w3;
        a4 += bfpair(u4) * w4;
        a5 += bfpair(u5) * w5;
        a6 += bfpair(u6) * w6;
        a7 += bfpair(u7) * w7;
    }
    for (; k + 4 <= end; k += 4) {
        int s0 = col[k], s1 = col[k + 1], s2 = col[k + 2], s3 = col[k + 3];
        float w0 = dis[s0], w1 = dis[s1], w2 = dis[s2], w3 = dis[s3];
        unsigned int u0 = h2p[s0 * 8 + c], u1 = h2p[s1 * 8 + c];
        unsigned int u2 = h2p[s2 * 8 + c], u3 = h2p[s3 * 8 + c];
        a0 += bfpair(u0) * w0;
        a1 += bfpair(u1) * w1;
        a2 += bfpair(u2) * w2;
        a3 += bfpair(u3) * w3;
    }
    for (; k < end; ++k) {
        int s = col[k];
        float w = dis[s];
        a0 += bfpair(h2p[s * 8 + c]) * w;
    }
    f32x2 r = ((a0 + a1) + (a2 + a3)) + ((a4 + a5) + (a6 + a7));
    float2 bb = ((const float2*)b2)[c];
    float v0 = r.x * dn + bb.x;
    float v1 = r.y * dn + bb.y;
    float m = fmaxf(v0, v1);
    #pragma unroll
    for (int off = 1; off < 8; off <<= 1) m = fmaxf(m, __shfl_xor(m, off, 8));
    float ssum = expf(v0 - m) + expf(v1 - m);
    #pragma unroll
    for (int off = 1; off < 8; off <<= 1) ssum += __shfl_xor(ssum, off, 8);
    float lg = m + logf(ssum);
    ((float2*)out)[node * 8 + c] = make_float2(v0 - lg, v1 - lg);
}

// ---------------- launch ----------------

extern "C" void kernel_launch(void* const* d_in, const int* in_sizes, int n_in,
                              void* d_out, int out_size, void* d_ws, size_t ws_size,
                              hipStream_t stream) {
    const float* x  = (const float*)d_in[0];
    const int*   ei = (const int*)d_in[1];
    const float* W1 = (const float*)d_in[2];
    const float* b1 = (const float*)d_in[3];
    const float* W2 = (const float*)d_in[4];
    const float* b2 = (const float*)d_in[5];
    float* out = (float*)d_out;

    const int* src = ei;              // edge_index[0]
    const int* dst = ei + N_EDGES;    // edge_index[1]

    // workspace (bytes), TOTAL = 58,440,960 (unchanged, proven safe R2-R10).
    // aliases: enc in xa's region (dead until gather1 writes xa, after place reads enc);
    //          h2b in xb's region (xb dead after gather1, mlp writes h2b later).
    char* ws = (char*)d_ws;
    ushort* xb  = (ushort*)(ws + 0);            // 25,600,000 (node-major bf16)
    ushort* h2b = (ushort*)(ws + 0);            //  3,200,000
    ushort* xa  = (ushort*)(ws + 25600000);     // 25,600,000 (node-major bf16)
    int*    enc = (int*)   (ws + 25600000);     //  6,400,000
    int*    col = (int*)   (ws + 51200000);     //  6,400,000
    float*  dis = (float*) (ws + 57600000);     //    400,000
    int*    cnt = (int*)   (ws + 58000000);     //    400,000
    int*    blk = (int*)   (ws + 58400000);     //      1,564
    ushort* W1T = (ushort*)(ws + 58404096);     //     32,768
    ushort* W2T = (ushort*)(ws + 58436864);     //      4,096

    zero_cnt_kernel    <<<NBLK, 256, 0, stream>>>(cnt);
    convert_deg_kernel <<<18822, 256, 0, stream>>>(x, W1, W2, src, dst, xb, W1T, W2T, cnt, enc);
    scan_blk_dis_kernel<<<NBLK, 256, 0, stream>>>(cnt, blk, dis);
    scan_top_kernel    <<<1, 512, 0, stream>>>(blk);
    place_kernel       <<<N_EDGES / 256, 256, 0, stream>>>(dst, enc, cnt, blk, col);

    gather1_kernel     <<<N_NODES / 4, 256, 0, stream>>>(col, cnt, blk, dis,
                                                         (const unsigned int*)xb,
                                                         (unsigned int*)xa);
    mlp_kernel         <<<1563, 256, 0, stream>>>(xa, W1T, b1, W2T, h2b);
    gather2_lsm_kernel <<<3125, 256, 0, stream>>>(col, cnt, blk, dis,
                                                  (const unsigned int*)h2b, b2, out);
}

// Round 12
// 318.708 us; speedup vs baseline: 1.5642x; 1.0074x over previous
//
#include <hip/hip_runtime.h>
#include <math.h>

#define N_NODES 100000
#define N_EDGES 1600000
#define NBLK 391   // ceil(100000/256)

typedef __attribute__((ext_vector_type(8))) short bf16x8;   // MFMA A/B frag (8 bf16)
typedef __attribute__((ext_vector_type(4))) float f32x4;    // MFMA C/D frag
typedef __attribute__((ext_vector_type(2))) float f32x2;    // packed pair -> v_pk_fma_f32

__device__ __forceinline__ unsigned short f2bf(float f) {   // RNE fp32->bf16
    unsigned int u = __float_as_uint(f);
    u += 0x7FFF + ((u >> 16) & 1);
    return (unsigned short)(u >> 16);
}
__device__ __forceinline__ float bf_lo(unsigned int u) { return __uint_as_float(u << 16); }
__device__ __forceinline__ float bf_hi(unsigned int u) { return __uint_as_float(u & 0xFFFF0000u); }
__device__ __forceinline__ f32x2 bfpair(unsigned int u) {
    f32x2 r; r.x = bf_lo(u); r.y = bf_hi(u); return r;
}

// ---------------- CSR build ----------------

// Zero the line-padded histogram: cnt16 has one counter per 64 B line (idx d*16).
__global__ __launch_bounds__(256) void zero_cnt16_kernel(int4* __restrict__ cnt16v) {
    int i = blockIdx.x * 256 + threadIdx.x;      // 1563*256*16B = 6.4MB (last block partial)
    if (i < 400000) cnt16v[i] = make_int4(0, 0, 0, 0);
}

// Merged: deg_count_rank (blocks 0..6249) + x->bf16 convert (6250..18749) + W converts.
// Histogram atomics hit cnt16[d*16]: ONE counter per 64 B line -> no same-line
// serialization (R11 theory: dense cnt had 256 atomics/line serializing ~400cyc each).
// enc[e] = src | (rank<<17): src < 2^17, rank < 2^15 (max in-deg ~45 for Poisson(16)).
__global__ __launch_bounds__(256) void convert_deg_kernel(const float* __restrict__ x,
                                                          const float* __restrict__ W1,
                                                          const float* __restrict__ W2,
                                                          const int* __restrict__ src,
                                                          const int* __restrict__ dst,
                                                          ushort* __restrict__ xb,
                                                          ushort* __restrict__ W1T,
                                                          ushort* __restrict__ W2T,
                                                          int* __restrict__ cnt16,
                                                          int* __restrict__ enc) {
    int b = blockIdx.x;
    if (b < 6250) {                                   // deg + rank capture
        int e = b * 256 + threadIdx.x;
        int r = atomicAdd(&cnt16[dst[e] * 16], 1);
        enc[e] = src[e] | (r << 17);
    } else if (b < 18750) {                           // x -> bf16 (node-major)
        int i = (b - 6250) * 256 + threadIdx.x;       // 12500 blocks, one float4 each
        float4 v = *(const float4*)&x[i * 4];
        ushort4 o;
        o.x = f2bf(v.x); o.y = f2bf(v.y); o.z = f2bf(v.z); o.w = f2bf(v.w);
        *(ushort4*)&xb[i * 4] = o;
    } else {                                          // 72 blocks: W1T / W2T
        int j = (b - 18750) * 256 + threadIdx.x;
        if (j < 16384) {
            int k = j >> 7, n = j & 127;              // W1[k][n] -> W1T[n][k]
            W1T[n * 128 + k] = f2bf(W1[j]);
        } else {
            int q = j - 16384;                        // 2048 elements
            int k = q >> 4, n = q & 15;               // W2[k][n] -> W2T[n][k]
            W2T[n * 128 + k] = f2bf(W2[q]);
        }
    }
}

// Fused: dis[i] = rsqrt(deg+1); exclusive scan of padded cnt16 -> compact cnt (+ block totals).
__global__ __launch_bounds__(256) void scan_blk_dis_kernel(const int* __restrict__ cnt16,
                                                           int* __restrict__ cnt,
                                                           int* __restrict__ blk,
                                                           float* __restrict__ dis) {
    __shared__ int s[256];
    int t = threadIdx.x, i = blockIdx.x * 256 + t;
    int v = (i < N_NODES) ? cnt16[i * 16] : 0;
    if (i < N_NODES) dis[i] = rsqrtf((float)v + 1.0f);
    s[t] = v;
    __syncthreads();
    for (int off = 1; off < 256; off <<= 1) {
        int u = (t >= off) ? s[t - off] : 0;
        __syncthreads();
        s[t] += u;
        __syncthreads();
    }
    if (i < N_NODES) cnt[i] = s[t] - v;           // exclusive within block
    if (t == 255) blk[blockIdx.x] = s[255];
}

__global__ __launch_bounds__(512) void scan_top_kernel(int* __restrict__ blk) {
    __shared__ int s[512];
    int t = threadIdx.x;
    int v = (t < NBLK) ? blk[t] : 0;
    s[t] = v;
    __syncthreads();
    for (int off = 1; off < 512; off <<= 1) {
        int u = (t >= off) ? s[t - off] : 0;
        __syncthreads();
        s[t] += u;
        __syncthreads();
    }
    if (t < NBLK) blk[t] = s[t] - v;
}

// Atomic-free placement (R5-R7 proven).
__global__ __launch_bounds__(256) void place_kernel(const int* __restrict__ dst,
                                                    const int* __restrict__ enc,
                                                    const int* __restrict__ cnt,
                                                    const int* __restrict__ blk,
                                                    int* __restrict__ col) {
    int e = blockIdx.x * 256 + threadIdx.x;
    int d = dst[e];
    int v = enc[e];
    col[cnt[d] + blk[d >> 8] + (v >> 17)] = v & 0x1FFFF;
}

// ---------------- layer-1 aggregation (wave=node, 64 lanes=128 feats, pk-fma) ----------------

__global__ __launch_bounds__(256) void gather1_kernel(const int* __restrict__ col,
                                                      const int* __restrict__ cnt,
                                                      const int* __restrict__ blk,
                                                      const float* __restrict__ dis,
                                                      const unsigned int* __restrict__ xb,
                                                      unsigned int* __restrict__ xa) {
    int t = threadIdx.x;
    int node = blockIdx.x * 4 + (t >> 6);        // 25000 blocks * 4 = 100000 exact
    int lane = t & 63;
    float dn = dis[node];
    int beg = cnt[node] + blk[node >> 8];
    int end = (node == N_NODES - 1) ? N_EDGES : cnt[node + 1] + blk[(node + 1) >> 8];
    unsigned int su = xb[node * 64 + lane];
    f32x2 a0 = bfpair(su) * dn;
    f32x2 a1 = {0.f, 0.f}, a2 = {0.f, 0.f}, a3 = {0.f, 0.f};
    f32x2 a4 = {0.f, 0.f}, a5 = {0.f, 0.f}, a6 = {0.f, 0.f}, a7 = {0.f, 0.f};
    int k = beg;
    for (; k + 8 <= end; k += 8) {
        int s0 = col[k], s1 = col[k + 1], s2 = col[k + 2], s3 = col[k + 3];
        int s4 = col[k + 4], s5 = col[k + 5], s6 = col[k + 6], s7 = col[k + 7];
        float w0 = dis[s0], w1 = dis[s1], w2 = dis[s2], w3 = dis[s3];
        float w4 = dis[s4], w5 = dis[s5], w6 = dis[s6], w7 = dis[s7];
        unsigned int u0 = xb[s0 * 64 + lane], u1 = xb[s1 * 64 + lane];
        unsigned int u2 = xb[s2 * 64 + lane], u3 = xb[s3 * 64 + lane];
        unsigned int u4 = xb[s4 * 64 + lane], u5 = xb[s5 * 64 + lane];
        unsigned int u6 = xb[s6 * 64 + lane], u7 = xb[s7 * 64 + lane];
        a0 += bfpair(u0) * w0;
        a1 += bfpair(u1) * w1;
        a2 += bfpair(u2) * w2;
        a3 += bfpair(u3) * w3;
        a4 += bfpair(u4) * w4;
        a5 += bfpair(u5) * w5;
        a6 += bfpair(u6) * w6;
        a7 += bfpair(u7) * w7;
    }
    for (; k + 4 <= end; k += 4) {
        int s0 = col[k], s1 = col[k + 1], s2 = col[k + 2], s3 = col[k + 3];
        float w0 = dis[s0], w1 = dis[s1], w2 = dis[s2], w3 = dis[s3];
        unsigned int u0 = xb[s0 * 64 + lane], u1 = xb[s1 * 64 + lane];
        unsigned int u2 = xb[s2 * 64 + lane], u3 = xb[s3 * 64 + lane];
        a0 += bfpair(u0) * w0;
        a1 += bfpair(u1) * w1;
        a2 += bfpair(u2) * w2;
        a3 += bfpair(u3) * w3;
    }
    for (; k < end; ++k) {
        int s = col[k];
        float w = dis[s];
        a0 += bfpair(xb[s * 64 + lane]) * w;
    }
    f32x2 r = (((a0 + a1) + (a2 + a3)) + ((a4 + a5) + (a6 + a7))) * dn;
    xa[node * 64 + lane] = (unsigned int)f2bf(r.x) | ((unsigned int)f2bf(r.y) << 16);
}

// ---------------- fused MLP: h2 = relu(xa@W1 + b1) @ W2, h2 emitted as bf16 ----------------

__global__ __launch_bounds__(256) void mlp_kernel(const ushort* __restrict__ xa,
                                                  const ushort* __restrict__ W1T,
                                                  const float* __restrict__ b1,
                                                  const ushort* __restrict__ W2T,
                                                  ushort* __restrict__ h2b) {
    __shared__ ushort sh[4][16][136];   // 136: keeps ds_read_b128 16B-aligned, banks spread
    int t = threadIdx.x;
    int wave = t >> 6, lane = t & 63;
    int l = lane & 15, quad = lane >> 4;
    int m0 = blockIdx.x * 64 + wave * 16;        // 1563*64 = 100032; waves past end idle
    bool valid = (m0 < N_NODES);                 // whole-wave predicate (no early return!)
    int row = valid ? (m0 + l) : 0;

    f32x4 acc[8] = {};
    #pragma unroll
    for (int kk = 0; kk < 4; ++kk) {
        bf16x8 a = *(const bf16x8*)&xa[row * 128 + kk * 32 + quad * 8];
        #pragma unroll
        for (int nt = 0; nt < 8; ++nt) {
            bf16x8 b = *(const bf16x8*)&W1T[(nt * 16 + l) * 128 + kk * 32 + quad * 8];
            acc[nt] = __builtin_amdgcn_mfma_f32_16x16x32_bf16(a, b, acc[nt], 0, 0, 0);
        }
    }
    #pragma unroll
    for (int nt = 0; nt < 8; ++nt) {
        float bias = b1[nt * 16 + l];
        #pragma unroll
        for (int r = 0; r < 4; ++r)
            sh[wave][quad * 4 + r][nt * 16 + l] = f2bf(fmaxf(acc[nt][r] + bias, 0.0f));
    }
    __syncthreads();   // all waves present — orders LDS writes->reads

    f32x4 acc2 = {};
    #pragma unroll
    for (int kk = 0; kk < 4; ++kk) {
        bf16x8 a2 = *(const bf16x8*)&sh[wave][l][kk * 32 + quad * 8];
        bf16x8 bw = *(const bf16x8*)&W2T[l * 128 + kk * 32 + quad * 8];
        acc2 = __builtin_amdgcn_mfma_f32_16x16x32_bf16(a2, bw, acc2, 0, 0, 0);
    }
    if (valid) {
        #pragma unroll
        for (int r = 0; r < 4; ++r)
            h2b[(m0 + quad * 4 + r) * 16 + l] = f2bf(acc2[r]);   // h2[m][n=l]
    }
}

// ---------------- layer-2 gather + bias + log-softmax (bf16 h2, 8 lanes/node, pk-fma) ----------------

__global__ __launch_bounds__(256) void gather2_lsm_kernel(const int* __restrict__ col,
                                                          const int* __restrict__ cnt,
                                                          const int* __restrict__ blk,
                                                          const float* __restrict__ dis,
                                                          const unsigned int* __restrict__ h2p,
                                                          const float* __restrict__ b2,
                                                          float* __restrict__ out) {
    int t = threadIdx.x;
    int node = blockIdx.x * 32 + (t >> 3);       // 3125 * 32 = 100000 exact
    int c = t & 7;                               // class pair: (2c, 2c+1)
    float dn = dis[node];
    int beg = cnt[node] + blk[node >> 8];
    int end = (node == N_NODES - 1) ? N_EDGES : cnt[node + 1] + blk[(node + 1) >> 8];
    unsigned int su = h2p[node * 8 + c];
    f32x2 a0 = bfpair(su) * dn;                  // self-loop term
    f32x2 a1 = {0.f, 0.f}, a2 = {0.f, 0.f}, a3 = {0.f, 0.f};
    f32x2 a4 = {0.f, 0.f}, a5 = {0.f, 0.f}, a6 = {0.f, 0.f}, a7 = {0.f, 0.f};
    int k = beg;
    for (; k + 8 <= end; k += 8) {
        int s0 = col[k], s1 = col[k + 1], s2 = col[k + 2], s3 = col[k + 3];
        int s4 = col[k + 4], s5 = col[k + 5], s6 = col[k + 6], s7 = col[k + 7];
        float w0 = dis[s0], w1 = dis[s1], w2 = dis[s2], w3 = dis[s3];
        float w4 = dis[s4], w5 = dis[s5], w6 = dis[s6], w7 = dis[s7];
        unsigned int u0 = h2p[s0 * 8 + c], u1 = h2p[s1 * 8 + c];
        unsigned int u2 = h2p[s2 * 8 + c], u3 = h2p[s3 * 8 + c];
        unsigned int u4 = h2p[s4 * 8 + c], u5 = h2p[s5 * 8 + c];
        unsigned int u6 = h2p[s6 * 8 + c], u7 = h2p[s7 * 8 + c];
        a0 += bfpair(u0) * w0;
        a1 += bfpair(u1) * w1;
        a2 += bfpair(u2) * w2;
        a3 += bfpair(u3) * w3;
        a4 += bfpair(u4) * w4;
        a5 += bfpair(u5) * w5;
        a6 += bfpair(u6) * w6;
        a7 += bfpair(u7) * w7;
    }
    for (; k + 4 <= end; k += 4) {
        int s0 = col[k], s1 = col[k + 1], s2 = col[k + 2], s3 = col[k + 3];
        float w0 = dis[s0], w1 = dis[s1], w2 = dis[s2], w3 = dis[s3];
        unsigned int u0 = h2p[s0 * 8 + c], u1 = h2p[s1 * 8 + c];
        unsigned int u2 = h2p[s2 * 8 + c], u3 = h2p[s3 * 8 + c];
        a0 += bfpair(u0) * w0;
        a1 += bfpair(u1) * w1;
        a2 += bfpair(u2) * w2;
        a3 += bfpair(u3) * w3;
    }
    for (; k < end; ++k) {
        int s = col[k];
        float w = dis[s];
        a0 += bfpair(h2p[s * 8 + c]) * w;
    }
    f32x2 r = ((a0 + a1) + (a2 + a3)) + ((a4 + a5) + (a6 + a7));
    float2 bb = ((const float2*)b2)[c];
    float v0 = r.x * dn + bb.x;
    float v1 = r.y * dn + bb.y;
    float m = fmaxf(v0, v1);
    #pragma unroll
    for (int off = 1; off < 8; off <<= 1) m = fmaxf(m, __shfl_xor(m, off, 8));
    float ssum = expf(v0 - m) + expf(v1 - m);
    #pragma unroll
    for (int off = 1; off < 8; off <<= 1) ssum += __shfl_xor(ssum, off, 8);
    float lg = m + logf(ssum);
    ((float2*)out)[node * 8 + c] = make_float2(v0 - lg, v1 - lg);
}

// ---------------- launch ----------------

extern "C" void kernel_launch(void* const* d_in, const int* in_sizes, int n_in,
                              void* d_out, int out_size, void* d_ws, size_t ws_size,
                              hipStream_t stream) {
    const float* x  = (const float*)d_in[0];
    const int*   ei = (const int*)d_in[1];
    const float* W1 = (const float*)d_in[2];
    const float* b1 = (const float*)d_in[3];
    const float* W2 = (const float*)d_in[4];
    const float* b2 = (const float*)d_in[5];
    float* out = (float*)d_out;

    const int* src = ei;              // edge_index[0]
    const int* dst = ei + N_EDGES;    // edge_index[1]

    // workspace (bytes), TOTAL = 58,440,960 (unchanged, proven safe R2-R11).
    // xa's region (25.6-51.2 MB) time-shares: enc (25.6-32.0) + cnt16 (32.0-38.4) during
    // CSR build; both dead before gather1 writes xa. h2b shares xb's region (dead post-gather1).
    char* ws = (char*)d_ws;
    ushort* xb    = (ushort*)(ws + 0);            // 25,600,000 (node-major bf16)
    ushort* h2b   = (ushort*)(ws + 0);            //  3,200,000
    ushort* xa    = (ushort*)(ws + 25600000);     // 25,600,000 (node-major bf16)
    int*    enc   = (int*)   (ws + 25600000);     //  6,400,000
    int*    cnt16 = (int*)   (ws + 32000000);     //  6,400,000 (line-padded histogram)
    int*    col   = (int*)   (ws + 51200000);     //  6,400,000
    float*  dis   = (float*) (ws + 57600000);     //    400,000
    int*    cnt   = (int*)   (ws + 58000000);     //    400,000 (compact scanned starts)
    int*    blk   = (int*)   (ws + 58400000);     //      1,564
    ushort* W1T   = (ushort*)(ws + 58404096);     //     32,768
    ushort* W2T   = (ushort*)(ws + 58436864);     //      4,096

    zero_cnt16_kernel  <<<1563, 256, 0, stream>>>((int4*)cnt16);
    convert_deg_kernel <<<18822, 256, 0, stream>>>(x, W1, W2, src, dst, xb, W1T, W2T, cnt16, enc);
    scan_blk_dis_kernel<<<NBLK, 256, 0, stream>>>(cnt16, cnt, blk, dis);
    scan_top_kernel    <<<1, 512, 0, stream>>>(blk);
    place_kernel       <<<N_EDGES / 256, 256, 0, stream>>>(dst, enc, cnt, blk, col);

    gather1_kernel     <<<N_NODES / 4, 256, 0, stream>>>(col, cnt, blk, dis,
                                                         (const unsigned int*)xb,
                                                         (unsigned int*)xa);
    mlp_kernel         <<<1563, 256, 0, stream>>>(xa, W1T, b1, W2T, h2b);
    gather2_lsm_kernel <<<3125, 256, 0, stream>>>(col, cnt, blk, dis,
                                                  (const unsigned int*)h2b, b2, out);
}